// Round 5
// baseline (213.248 us; speedup 1.0000x reference)
//
#include <hip/hip_runtime.h>
#include <hip/hip_bf16.h>

typedef __bf16 bf16;
typedef __bf16 bf16x4 __attribute__((ext_vector_type(4)));
typedef __bf16 bf16x8 __attribute__((ext_vector_type(8)));
typedef float f32x4 __attribute__((ext_vector_type(4)));

typedef __attribute__((address_space(3))) void lds_void;
typedef const __attribute__((address_space(1))) void gbl_void;

#define D_MODEL 1024
#define NHEAD 16
#define DEPTH 64
#define SEQ 2048
#define BATCH 2
#define NTOK (BATCH * SEQ)   // 4096

// 1/sqrt(64) * log2(e): folded into q so attention exp is a bare exp2.
#define Q_SCALE 0.18033688f

// ---------------------------------------------------------------------------
// Kernel 1: prep = weight transpose+convert (z=0..3) + x convert (z=4..7).
// ---------------------------------------------------------------------------
__global__ __launch_bounds__(256) void prep(const float* __restrict__ w0,
                                            const float* __restrict__ w1,
                                            const float* __restrict__ w2,
                                            const float* __restrict__ w3,
                                            const float* __restrict__ x,
                                            bf16* __restrict__ wtb,
                                            bf16* __restrict__ xb) {
    int z = blockIdx.z;
    int tx = threadIdx.x, ty = threadIdx.y;   // (32, 8)
    if (z < 4) {
        const float* w = (z == 0) ? w0 : (z == 1) ? w1 : (z == 2) ? w2 : w3;
        bf16* d = wtb + (size_t)z * D_MODEL * D_MODEL;
        __shared__ float tile[32][33];
        int c0 = blockIdx.x * 32;   // source col block (n)
        int r0 = blockIdx.y * 32;   // source row block (k)
#pragma unroll
        for (int i = 0; i < 4; i++)
            tile[ty + i * 8][tx] = w[(size_t)(r0 + ty + i * 8) * D_MODEL + c0 + tx];
        __syncthreads();
#pragma unroll
        for (int i = 0; i < 4; i++)
            d[(size_t)(c0 + ty + i * 8) * D_MODEL + r0 + tx] = (bf16)tile[tx][ty + i * 8];
    } else {
        int t = ty * 32 + tx;
        size_t i = ((size_t)(z - 4) * 1024 + blockIdx.y * 32 + blockIdx.x) * 256 + t;
        float4 v = ((const float4*)x)[i];
        bf16x4 o = {(bf16)v.x, (bf16)v.y, (bf16)v.z, (bf16)v.w};
        *(bf16x4*)&xb[i * 4] = o;
    }
}

// ---------------------------------------------------------------------------
// Kernel 2: QKV projection, 256x256 tile, BK=64, 8 waves, 8-phase counted
// vmcnt schedule (unchanged this round).
// ---------------------------------------------------------------------------
__global__ __launch_bounds__(512, 2) void qkv_gemm(const bf16* __restrict__ xb,
                                                   const bf16* __restrict__ wtb,
                                                   const float* __restrict__ bq,
                                                   const float* __restrict__ bk,
                                                   const float* __restrict__ bv,
                                                   bf16* __restrict__ q,
                                                   bf16* __restrict__ k,
                                                   bf16* __restrict__ v) {
    __shared__ bf16 sm[65536];   // 128 KiB

    const int flat = blockIdx.x;
    const int wg = (flat & 7) * 24 + (flat >> 3);
    const int mt = wg & 15, nt = wg >> 4;     // wg = nt*16 + mt
    const int row0 = mt << 8;                 // token base
    const int z = nt >> 2;                    // 0=q 1=k 2=v
    const int nb = (nt & 3) << 8;             // feature base within z

    const int tid = threadIdx.x;
    const int lane = tid & 63, wave = tid >> 6;
    const int wm = wave >> 2, wn = wave & 3;  // 2 x 4 wave grid
    const int quad = lane >> 4, l16 = lane & 15;
    const int kch = ((quad ^ ((l16 >> 1) & 3)) << 3);   // swizzled 16B chunk (elems)

    const int srow = lane >> 2;
    const int scg = (lane & 3) ^ ((lane >> 3) & 3);     // pre-swizzled src chunk
    const int stDst = wave * 1024 + lane * 8;           // elems within half

    const bf16* Ag = xb + (size_t)(row0 + wave * 32 + srow) * D_MODEL + scg * 8;
    const bf16* Bg = wtb + (size_t)z * D_MODEL * D_MODEL
                   + (size_t)(nb + wave * 32 + srow) * D_MODEL + scg * 8;

    f32x4 acc[8][4] = {};
    bf16x8 bfr[4];

#define GLL(SRC, DST) __builtin_amdgcn_global_load_lds((gbl_void*)(SRC), (lds_void*)(DST), 16, 0, 0)
#define STG_A(T_, KQ_, BUF_) { \
    const bf16* s_ = Ag + (T_) * 64 + (KQ_) * 32; \
    bf16* d_ = sm + (BUF_) * 16384 + (KQ_) * 8192 + stDst; \
    GLL(s_, d_); GLL(s_ + 16 * D_MODEL, d_ + 512); }
#define STG_B(T_, KQ_, BUF_) { \
    const bf16* s_ = Bg + (T_) * 64 + (KQ_) * 32; \
    bf16* d_ = sm + 32768 + (BUF_) * 16384 + (KQ_) * 8192 + stDst; \
    GLL(s_, d_); GLL(s_ + 16 * D_MODEL, d_ + 512); }
#define WAIT6 { asm volatile("s_waitcnt vmcnt(6)" ::: "memory"); }
#define NOW

#define PHASE(BUF_, KQ_, MQ_, STG_STMT, WAIT_STMT) { \
    bf16x8 af[4]; \
    const int ab_ = (BUF_) * 16384 + (KQ_) * 8192 + (wm * 128 + (MQ_) * 64 + l16) * 32 + kch; \
    _Pragma("unroll") \
    for (int i_ = 0; i_ < 4; i_++) af[i_] = *(const bf16x8*)&sm[ab_ + i_ * 512]; \
    if ((MQ_) == 0) { \
        const int bb_ = 32768 + (BUF_) * 16384 + (KQ_) * 8192 + (wn * 64 + l16) * 32 + kch; \
        _Pragma("unroll") \
        for (int j_ = 0; j_ < 4; j_++) bfr[j_] = *(const bf16x8*)&sm[bb_ + j_ * 512]; \
    } \
    STG_STMT; \
    WAIT_STMT; \
    __builtin_amdgcn_sched_barrier(0); \
    __builtin_amdgcn_s_barrier(); \
    __builtin_amdgcn_s_setprio(1); \
    _Pragma("unroll") \
    for (int i_ = 0; i_ < 4; i_++) \
        _Pragma("unroll") \
        for (int j_ = 0; j_ < 4; j_++) \
            acc[(MQ_) * 4 + i_][j_] = __builtin_amdgcn_mfma_f32_16x16x32_bf16( \
                af[i_], bfr[j_], acc[(MQ_) * 4 + i_][j_], 0, 0, 0); \
    __builtin_amdgcn_s_setprio(0); \
    __builtin_amdgcn_sched_barrier(0); \
    __builtin_amdgcn_s_barrier(); }

    STG_B(0, 0, 0);
    STG_A(0, 0, 0);
    STG_B(0, 1, 0);
    STG_A(0, 1, 0);
    asm volatile("s_waitcnt vmcnt(4)" ::: "memory");
    STG_B(1, 0, 1);
    STG_A(1, 0, 1);
    STG_B(1, 1, 1);
    asm volatile("s_waitcnt vmcnt(6)" ::: "memory");
    __builtin_amdgcn_sched_barrier(0);
    __builtin_amdgcn_s_barrier();

#pragma unroll 1
    for (int it = 0; it < 8; ++it) {
        const int t1 = 2 * it + 1;
        const int t2 = (2 * it + 2) & 15;   // wrap keeps vmcnt counts exact at tail
        const int t3 = (2 * it + 3) & 15;
        PHASE(0, 0, 0, STG_A(t1, 1, 1), NOW)      // ph1
        PHASE(0, 0, 1, STG_B(t2, 0, 0), NOW)      // ph2
        PHASE(0, 1, 0, STG_A(t2, 0, 0), NOW)      // ph3
        PHASE(0, 1, 1, STG_B(t2, 1, 0), WAIT6)    // ph4
        PHASE(1, 0, 0, STG_A(t2, 1, 0), NOW)      // ph5
        PHASE(1, 0, 1, STG_B(t3, 0, 1), NOW)      // ph6
        PHASE(1, 1, 0, STG_A(t3, 0, 1), NOW)      // ph7
        PHASE(1, 1, 1, STG_B(t3, 1, 1), WAIT6)    // ph8
    }

#undef PHASE
#undef WAIT6
#undef NOW
#undef STG_A
#undef STG_B
#undef GLL

    const float* bias = (z == 0) ? bq : (z == 1) ? bk : bv;
    const int bI = row0 >> 11;
    const int sBase = row0 & 2047;
    if (z < 2) {
        bf16* dst = (z == 0) ? q : k;   // [B,H,S,64]
        const float scl = (z == 0) ? Q_SCALE : 1.0f;
#pragma unroll
        for (int j = 0; j < 4; j++) {
            const int f = nb + wn * 64 + j * 16 + l16;
            const float bi = bias[f];
            const int hh = f >> 6, d = f & 63;
            bf16* dcol = dst + ((size_t)(bI * NHEAD + hh) * SEQ) * DEPTH + d;
#pragma unroll
            for (int mi = 0; mi < 8; mi++) {
                const int s0 = sBase + wm * 128 + (mi >> 2) * 64 + (mi & 3) * 16 + quad * 4;
#pragma unroll
                for (int r = 0; r < 4; r++)
                    dcol[(size_t)(s0 + r) * DEPTH] = (bf16)((acc[mi][j][r] + bi) * scl);
            }
        }
    } else {
#pragma unroll
        for (int j = 0; j < 4; j++) {
            const int f = nb + wn * 64 + j * 16 + l16;
            const float bi = bias[f];
            const int hh = f >> 6, d = f & 63;
            bf16* vrow = v + ((size_t)(bI * NHEAD + hh) * DEPTH + d) * SEQ;
#pragma unroll
            for (int mi = 0; mi < 8; mi++) {
                const int s0 = sBase + wm * 128 + (mi >> 2) * 64 + (mi & 3) * 16 + quad * 4;
                f32x4 a = acc[mi][j];
                bf16x4 ob = {(bf16)(a[0] + bi), (bf16)(a[1] + bi),
                             (bf16)(a[2] + bi), (bf16)(a[3] + bi)};
                *(bf16x4*)&vrow[s0] = ob;
            }
        }
    }
}

// ---------------------------------------------------------------------------
// Kernel 3: flash attention, R8: barrier-free, LDS-free main loop.
// Block = 64 q rows x head, 4 waves; kv tile 128, wave owns a 32-kv slice.
// R3's verified dataflow (P in regs via swapped QK^T token map) with BOTH
// K and V register-prefetched one compute-phase ahead (R3's flaw was V
// loaded at point of use).  sched_barrier(0) after each load block pins
// issue-early order; compiler then emits counted vmcnt waits (first QK
// MFMA waits only on ka, PV waits only on va).  No __syncthreads, no LDS
// in the loop -> waves fully self-paced; MFMA/trans/VALU pipes interleave
// across resident waves.  All K/V loads are full-sector b128.  Cross-wave
// kv-partial reduction at the end (R4's verified code, 36 KB LDS).
// XCD pinning: block id = bh + 32*qb -> XCD bh%8, 4 heads = 2 MB KV / L2.
// ---------------------------------------------------------------------------
__global__ __launch_bounds__(256) void attn(const bf16* __restrict__ q,
                                            const bf16* __restrict__ k,
                                            const bf16* __restrict__ v,
                                            bf16* __restrict__ ctx) {
    __shared__ __align__(16) char smem[36864];   // reduction only
    const int tid = threadIdx.x;
    const int lane = tid & 63, wave = tid >> 6;
    const int quad = lane >> 4, l16 = lane & 15;
    const int bh = blockIdx.x;
    const int q0 = blockIdx.y * 64;
    const size_t hb = (size_t)bh * SEQ * DEPTH;
    const bf16* qh = q + hb;
    const bf16* kh = k + hb;            // [S][64]
    const bf16* vh = v + hb;            // [64][S]

    // Q as B-fragments: block's 64 q rows, shared by all waves
    bf16x8 bq_[4][2];
#pragma unroll
    for (int n = 0; n < 4; n++) {
        int qrow = q0 + n * 16 + l16;
#pragma unroll
        for (int c = 0; c < 2; c++)
            bq_[n][c] = *(const bf16x8*)&qh[(size_t)qrow * DEPTH + c * 32 + quad * 8];
    }

    // per-lane fixed offsets (R3's verified token map)
    const int klane = (wave * 32 + ((l16 >> 2) << 3) + (l16 & 3)) * DEPTH + quad * 8;
    const int vlane = l16 * SEQ + wave * 32 + quad * 8;

    f32x4 ov[4][4] = {};   // [d-tile][q-tile] kv-partial ctx^T
    f32x4 lv = {};         // [q-tile] quad-partial row sums

    bf16x8 ka[2][2], kb2[2][2];   // K frags [h][c], double-buffered
    bf16x8 va[4], vb[4];          // V frags [d-tile], one per half

#define LOADK(KF, T_) { \
    const bf16* kp_ = kh + (size_t)(T_) * DEPTH + klane; \
    KF[0][0] = *(const bf16x8*)(kp_); \
    KF[0][1] = *(const bf16x8*)(kp_ + 32); \
    KF[1][0] = *(const bf16x8*)(kp_ + 256); \
    KF[1][1] = *(const bf16x8*)(kp_ + 288); }

#define LOADV(VF, T_) { \
    const bf16* vp_ = vh + vlane + (T_); \
    VF[0] = *(const bf16x8*)(vp_); \
    VF[1] = *(const bf16x8*)(vp_ + 16 * SEQ); \
    VF[2] = *(const bf16x8*)(vp_ + 32 * SEQ); \
    VF[3] = *(const bf16x8*)(vp_ + 48 * SEQ); }

#define COMPUTE(KF, VF) { \
    f32x4 s0[4] = {}, s1[4] = {}; \
    _Pragma("unroll") \
    for (int n_ = 0; n_ < 4; n_++) { \
        s0[n_] = __builtin_amdgcn_mfma_f32_16x16x32_bf16(KF[0][0], bq_[n_][0], s0[n_], 0, 0, 0); \
        s0[n_] = __builtin_amdgcn_mfma_f32_16x16x32_bf16(KF[0][1], bq_[n_][1], s0[n_], 0, 0, 0); \
        s1[n_] = __builtin_amdgcn_mfma_f32_16x16x32_bf16(KF[1][0], bq_[n_][0], s1[n_], 0, 0, 0); \
        s1[n_] = __builtin_amdgcn_mfma_f32_16x16x32_bf16(KF[1][1], bq_[n_][1], s1[n_], 0, 0, 0); \
    } \
    bf16x8 pb[4]; \
    _Pragma("unroll") \
    for (int n_ = 0; n_ < 4; n_++) { \
        float e0 = __builtin_amdgcn_exp2f(s0[n_][0]); \
        float e1 = __builtin_amdgcn_exp2f(s0[n_][1]); \
        float e2 = __builtin_amdgcn_exp2f(s0[n_][2]); \
        float e3 = __builtin_amdgcn_exp2f(s0[n_][3]); \
        float e4 = __builtin_amdgcn_exp2f(s1[n_][0]); \
        float e5 = __builtin_amdgcn_exp2f(s1[n_][1]); \
        float e6 = __builtin_amdgcn_exp2f(s1[n_][2]); \
        float e7 = __builtin_amdgcn_exp2f(s1[n_][3]); \
        pb[n_][0] = (bf16)e0; pb[n_][1] = (bf16)e1; \
        pb[n_][2] = (bf16)e2; pb[n_][3] = (bf16)e3; \
        pb[n_][4] = (bf16)e4; pb[n_][5] = (bf16)e5; \
        pb[n_][6] = (bf16)e6; pb[n_][7] = (bf16)e7; \
        lv[n_] += ((e0 + e1) + (e2 + e3)) + ((e4 + e5) + (e6 + e7)); \
    } \
    _Pragma("unroll") \
    for (int t_ = 0; t_ < 4; t_++) \
        _Pragma("unroll") \
        for (int n_ = 0; n_ < 4; n_++) \
            ov[t_][n_] = __builtin_amdgcn_mfma_f32_16x16x32_bf16(VF[t_], pb[n_], ov[t_][n_], 0, 0, 0); }

    LOADK(ka, 0);
#pragma unroll 1
    for (int tt = 0; tt < SEQ; tt += 256) {
        LOADV(va, tt);
        LOADK(kb2, tt + 128);
        __builtin_amdgcn_sched_barrier(0);
        COMPUTE(ka, va);
        LOADV(vb, tt + 128);
        LOADK(ka, (tt + 256) & (SEQ - 1));   // wrap: valid mem, data unused
        __builtin_amdgcn_sched_barrier(0);
        COMPUTE(kb2, vb);
    }
#undef COMPUTE
#undef LOADV
#undef LOADK

    // ---- cross-wave reduction of kv-partials (R4 verified) ----
    f32x4* Red  = (f32x4*)smem;              // [8 tiles][4 waves][64]  32 KB
    f32x4* Lred = (f32x4*)(smem + 32768);    // [4 waves][64]            4 KB
    __syncthreads();
#pragma unroll
    for (int tt = 0; tt < 8; tt++)
        Red[(tt * 4 + wave) * 64 + lane] = ov[tt >> 2][tt & 3];
    Lred[wave * 64 + lane] = lv;
    __syncthreads();
    f32x4 ls = {};
#pragma unroll
    for (int w_ = 0; w_ < 4; w_++)
#pragma unroll
        for (int qd = 0; qd < 4; qd++)
            ls += Lred[w_ * 64 + qd * 16 + l16];
    const int b = bh >> 4, hh = bh & 15;
    const int wb1 = wave & 1;
#pragma unroll
    for (int u = 0; u < 2; u++) {
        int tt = wave * 2 + u;
        f32x4 sv = Red[(tt * 4 + 0) * 64 + lane] + Red[(tt * 4 + 1) * 64 + lane]
                 + Red[(tt * 4 + 2) * 64 + lane] + Red[(tt * 4 + 3) * 64 + lane];
        int n = wb1 * 2 + u, t = wave >> 1;
        float iv = 1.0f / (wb1 ? ls[2 + u] : ls[u]);
        bf16x4 ob = {(bf16)(sv[0] * iv), (bf16)(sv[1] * iv),
                     (bf16)(sv[2] * iv), (bf16)(sv[3] * iv)};
        size_t off = ((size_t)(b * SEQ + q0 + n * 16 + l16)) * D_MODEL
                   + hh * 64 + t * 16 + quad * 4;
        *(bf16x4*)&ctx[off] = ob;
    }
    __syncthreads();
#pragma unroll
    for (int tt = 8; tt < 16; tt++)
        Red[((tt - 8) * 4 + wave) * 64 + lane] = ov[tt >> 2][tt & 3];
    __syncthreads();
#pragma unroll
    for (int u = 0; u < 2; u++) {
        int tt = 8 + wave * 2 + u;
        int rt = tt - 8;
        f32x4 sv = Red[(rt * 4 + 0) * 64 + lane] + Red[(rt * 4 + 1) * 64 + lane]
                 + Red[(rt * 4 + 2) * 64 + lane] + Red[(rt * 4 + 3) * 64 + lane];
        int n = wb1 * 2 + u, t = 2 + (wave >> 1);
        float iv = 1.0f / (wb1 ? ls[2 + u] : ls[u]);
        bf16x4 ob = {(bf16)(sv[0] * iv), (bf16)(sv[1] * iv),
                     (bf16)(sv[2] * iv), (bf16)(sv[3] * iv)};
        size_t off = ((size_t)(b * SEQ + q0 + n * 16 + l16)) * D_MODEL
                   + hh * 64 + t * 16 + quad * 4;
        *(bf16x4*)&ctx[off] = ob;
    }
}

// ---------------------------------------------------------------------------
// Kernel 4: output projection (unchanged this round).
// ---------------------------------------------------------------------------
__global__ __launch_bounds__(256) void out_gemm(const bf16* __restrict__ ctx,
                                                const bf16* __restrict__ wot,
                                                const float* __restrict__ bo,
                                                float* __restrict__ out) {
    __shared__ bf16 As[64 * 32];
    __shared__ bf16 Bs[128 * 32];
    const int tid = threadIdx.x;
    const int lane = tid & 63, wave = tid >> 6;
    const int quad = lane >> 4, l16 = lane & 15;
    const int srow = lane >> 2, selem = (lane & 3) * 8;
    int row0 = blockIdx.y * 64, col0 = blockIdx.x * 128;
    f32x4 acc[4][2] = {};

    for (int k0 = 0; k0 < D_MODEL; k0 += 32) {
        __syncthreads();
        {
            const bf16* ga = ctx + (size_t)(row0 + wave * 16 + srow) * D_MODEL + k0 + selem;
            __builtin_amdgcn_global_load_lds((gbl_void*)ga, (lds_void*)(As + wave * 512 + lane * 8), 16, 0, 0);
        }
#pragma unroll
        for (int t = 0; t < 2; t++) {
            int m = wave * 2 + t;
            const bf16* gb = wot + (size_t)(col0 + m * 16 + srow) * D_MODEL + k0 + selem;
            __builtin_amdgcn_global_load_lds((gbl_void*)gb, (lds_void*)(Bs + m * 512 + lane * 8), 16, 0, 0);
        }
        __syncthreads();
        bf16x8 af[4], bfr[2];
#pragma unroll
        for (int i = 0; i < 4; i++)
            af[i] = *(const bf16x8*)&As[(i * 16 + l16) * 32 + quad * 8];
#pragma unroll
        for (int j = 0; j < 2; j++)
            bfr[j] = *(const bf16x8*)&Bs[(wave * 32 + j * 16 + l16) * 32 + quad * 8];
#pragma unroll
        for (int i = 0; i < 4; i++)
#pragma unroll
            for (int j = 0; j < 2; j++)
                acc[i][j] = __builtin_amdgcn_mfma_f32_16x16x32_bf16(af[i], bfr[j], acc[i][j], 0, 0, 0);
    }
#pragma unroll
    for (int i = 0; i < 4; i++)
#pragma unroll
        for (int j = 0; j < 2; j++) {
            int colg = col0 + wave * 32 + j * 16 + l16;
            float bi = bo[colg];
            int rbase = row0 + i * 16 + quad * 4;
#pragma unroll
            for (int r = 0; r < 4; r++)
                out[(size_t)(rbase + r) * D_MODEL + colg] = acc[i][j][r] + bi;
        }
}

// ---------------------------------------------------------------------------
extern "C" void kernel_launch(void* const* d_in, const int* in_sizes, int n_in,
                              void* d_out, int out_size, void* d_ws, size_t ws_size,
                              hipStream_t stream) {
    const float* x  = (const float*)d_in[0];
    const float* wq = (const float*)d_in[1];
    const float* bq = (const float*)d_in[2];
    const float* wk = (const float*)d_in[3];
    const float* bk = (const float*)d_in[4];
    const float* wv = (const float*)d_in[5];
    const float* bv = (const float*)d_in[6];
    const float* wo = (const float*)d_in[7];
    const float* bo = (const float*)d_in[8];
    float* out = (float*)d_out;

    const size_t MB = 1024 * 1024;
    char* ws = (char*)d_ws;
    bf16* xb  = (bf16*)(ws);             // [4096][1024]            8 MB
    bf16* wtb = (bf16*)(ws + 8 * MB);    // [4][1024][1024] (N,K)   8 MB
    bf16* qb  = (bf16*)(ws + 16 * MB);   // [B,H,S,64] (scaled)     8 MB
    bf16* kb  = (bf16*)(ws + 24 * MB);   // [B,H,S,64]              8 MB
    bf16* vb  = (bf16*)(ws + 32 * MB);   // [B,H,64,S]              8 MB
    bf16* ctx = (bf16*)(ws + 40 * MB);   // [4096][1024]            8 MB

    prep<<<dim3(32, 32, 8), dim3(32, 8), 0, stream>>>(wq, wk, wv, wo, x, wtb, xb);
    qkv_gemm<<<dim3(192), dim3(512), 0, stream>>>(xb, wtb, bq, bk, bv, qb, kb, vb);
    attn<<<dim3(BATCH * NHEAD, SEQ / 64), 256, 0, stream>>>(qb, kb, vb, ctx);
    out_gemm<<<dim3(8, 64), 256, 0, stream>>>(ctx, wtb + 3 * (size_t)D_MODEL * D_MODEL, bo, out);
}

// Round 6
// 187.190 us; speedup vs baseline: 1.1392x; 1.1392x over previous
//
#include <hip/hip_runtime.h>
#include <hip/hip_bf16.h>

typedef __bf16 bf16;
typedef __bf16 bf16x4 __attribute__((ext_vector_type(4)));
typedef __bf16 bf16x8 __attribute__((ext_vector_type(8)));
typedef float f32x4 __attribute__((ext_vector_type(4)));

typedef __attribute__((address_space(3))) void lds_void;
typedef const __attribute__((address_space(1))) void gbl_void;

#define D_MODEL 1024
#define NHEAD 16
#define DEPTH 64
#define SEQ 2048
#define BATCH 2
#define NTOK (BATCH * SEQ)   // 4096

// 1/sqrt(64) * log2(e): folded into q so attention exp is a bare exp2.
#define Q_SCALE 0.18033688f

// ---------------------------------------------------------------------------
// Kernel 1: prep = weight transpose+convert (z=0..3) + x convert (z=4..7).
// ---------------------------------------------------------------------------
__global__ __launch_bounds__(256) void prep(const float* __restrict__ w0,
                                            const float* __restrict__ w1,
                                            const float* __restrict__ w2,
                                            const float* __restrict__ w3,
                                            const float* __restrict__ x,
                                            bf16* __restrict__ wtb,
                                            bf16* __restrict__ xb) {
    int z = blockIdx.z;
    int tx = threadIdx.x, ty = threadIdx.y;   // (32, 8)
    if (z < 4) {
        const float* w = (z == 0) ? w0 : (z == 1) ? w1 : (z == 2) ? w2 : w3;
        bf16* d = wtb + (size_t)z * D_MODEL * D_MODEL;
        __shared__ float tile[32][33];
        int c0 = blockIdx.x * 32;   // source col block (n)
        int r0 = blockIdx.y * 32;   // source row block (k)
#pragma unroll
        for (int i = 0; i < 4; i++)
            tile[ty + i * 8][tx] = w[(size_t)(r0 + ty + i * 8) * D_MODEL + c0 + tx];
        __syncthreads();
#pragma unroll
        for (int i = 0; i < 4; i++)
            d[(size_t)(c0 + ty + i * 8) * D_MODEL + r0 + tx] = (bf16)tile[tx][ty + i * 8];
    } else {
        int t = ty * 32 + tx;
        size_t i = ((size_t)(z - 4) * 1024 + blockIdx.y * 32 + blockIdx.x) * 256 + t;
        float4 v = ((const float4*)x)[i];
        bf16x4 o = {(bf16)v.x, (bf16)v.y, (bf16)v.z, (bf16)v.w};
        *(bf16x4*)&xb[i * 4] = o;
    }
}

// ---------------------------------------------------------------------------
// Kernel 2: QKV projection, 256x256 tile, BK=64, 8 waves, 8-phase counted
// vmcnt schedule (unchanged this round).
// ---------------------------------------------------------------------------
__global__ __launch_bounds__(512, 2) void qkv_gemm(const bf16* __restrict__ xb,
                                                   const bf16* __restrict__ wtb,
                                                   const float* __restrict__ bq,
                                                   const float* __restrict__ bk,
                                                   const float* __restrict__ bv,
                                                   bf16* __restrict__ q,
                                                   bf16* __restrict__ k,
                                                   bf16* __restrict__ v) {
    __shared__ bf16 sm[65536];   // 128 KiB

    const int flat = blockIdx.x;
    const int wg = (flat & 7) * 24 + (flat >> 3);
    const int mt = wg & 15, nt = wg >> 4;     // wg = nt*16 + mt
    const int row0 = mt << 8;                 // token base
    const int z = nt >> 2;                    // 0=q 1=k 2=v
    const int nb = (nt & 3) << 8;             // feature base within z

    const int tid = threadIdx.x;
    const int lane = tid & 63, wave = tid >> 6;
    const int wm = wave >> 2, wn = wave & 3;  // 2 x 4 wave grid
    const int quad = lane >> 4, l16 = lane & 15;
    const int kch = ((quad ^ ((l16 >> 1) & 3)) << 3);   // swizzled 16B chunk (elems)

    const int srow = lane >> 2;
    const int scg = (lane & 3) ^ ((lane >> 3) & 3);     // pre-swizzled src chunk
    const int stDst = wave * 1024 + lane * 8;           // elems within half

    const bf16* Ag = xb + (size_t)(row0 + wave * 32 + srow) * D_MODEL + scg * 8;
    const bf16* Bg = wtb + (size_t)z * D_MODEL * D_MODEL
                   + (size_t)(nb + wave * 32 + srow) * D_MODEL + scg * 8;

    f32x4 acc[8][4] = {};
    bf16x8 bfr[4];

#define GLL(SRC, DST) __builtin_amdgcn_global_load_lds((gbl_void*)(SRC), (lds_void*)(DST), 16, 0, 0)
#define STG_A(T_, KQ_, BUF_) { \
    const bf16* s_ = Ag + (T_) * 64 + (KQ_) * 32; \
    bf16* d_ = sm + (BUF_) * 16384 + (KQ_) * 8192 + stDst; \
    GLL(s_, d_); GLL(s_ + 16 * D_MODEL, d_ + 512); }
#define STG_B(T_, KQ_, BUF_) { \
    const bf16* s_ = Bg + (T_) * 64 + (KQ_) * 32; \
    bf16* d_ = sm + 32768 + (BUF_) * 16384 + (KQ_) * 8192 + stDst; \
    GLL(s_, d_); GLL(s_ + 16 * D_MODEL, d_ + 512); }
#define WAIT6 { asm volatile("s_waitcnt vmcnt(6)" ::: "memory"); }
#define NOW

#define PHASE(BUF_, KQ_, MQ_, STG_STMT, WAIT_STMT) { \
    bf16x8 af[4]; \
    const int ab_ = (BUF_) * 16384 + (KQ_) * 8192 + (wm * 128 + (MQ_) * 64 + l16) * 32 + kch; \
    _Pragma("unroll") \
    for (int i_ = 0; i_ < 4; i_++) af[i_] = *(const bf16x8*)&sm[ab_ + i_ * 512]; \
    if ((MQ_) == 0) { \
        const int bb_ = 32768 + (BUF_) * 16384 + (KQ_) * 8192 + (wn * 64 + l16) * 32 + kch; \
        _Pragma("unroll") \
        for (int j_ = 0; j_ < 4; j_++) bfr[j_] = *(const bf16x8*)&sm[bb_ + j_ * 512]; \
    } \
    STG_STMT; \
    WAIT_STMT; \
    __builtin_amdgcn_sched_barrier(0); \
    __builtin_amdgcn_s_barrier(); \
    __builtin_amdgcn_s_setprio(1); \
    _Pragma("unroll") \
    for (int i_ = 0; i_ < 4; i_++) \
        _Pragma("unroll") \
        for (int j_ = 0; j_ < 4; j_++) \
            acc[(MQ_) * 4 + i_][j_] = __builtin_amdgcn_mfma_f32_16x16x32_bf16( \
                af[i_], bfr[j_], acc[(MQ_) * 4 + i_][j_], 0, 0, 0); \
    __builtin_amdgcn_s_setprio(0); \
    __builtin_amdgcn_sched_barrier(0); \
    __builtin_amdgcn_s_barrier(); }

    STG_B(0, 0, 0);
    STG_A(0, 0, 0);
    STG_B(0, 1, 0);
    STG_A(0, 1, 0);
    asm volatile("s_waitcnt vmcnt(4)" ::: "memory");
    STG_B(1, 0, 1);
    STG_A(1, 0, 1);
    STG_B(1, 1, 1);
    asm volatile("s_waitcnt vmcnt(6)" ::: "memory");
    __builtin_amdgcn_sched_barrier(0);
    __builtin_amdgcn_s_barrier();

#pragma unroll 1
    for (int it = 0; it < 8; ++it) {
        const int t1 = 2 * it + 1;
        const int t2 = (2 * it + 2) & 15;   // wrap keeps vmcnt counts exact at tail
        const int t3 = (2 * it + 3) & 15;
        PHASE(0, 0, 0, STG_A(t1, 1, 1), NOW)      // ph1
        PHASE(0, 0, 1, STG_B(t2, 0, 0), NOW)      // ph2
        PHASE(0, 1, 0, STG_A(t2, 0, 0), NOW)      // ph3
        PHASE(0, 1, 1, STG_B(t2, 1, 0), WAIT6)    // ph4
        PHASE(1, 0, 0, STG_A(t2, 1, 0), NOW)      // ph5
        PHASE(1, 0, 1, STG_B(t3, 0, 1), NOW)      // ph6
        PHASE(1, 1, 0, STG_A(t3, 0, 1), NOW)      // ph7
        PHASE(1, 1, 1, STG_B(t3, 1, 1), WAIT6)    // ph8
    }

#undef PHASE
#undef WAIT6
#undef NOW
#undef STG_A
#undef STG_B
#undef GLL

    const float* bias = (z == 0) ? bq : (z == 1) ? bk : bv;
    const int bI = row0 >> 11;
    const int sBase = row0 & 2047;
    if (z < 2) {
        bf16* dst = (z == 0) ? q : k;   // [B,H,S,64]
        const float scl = (z == 0) ? Q_SCALE : 1.0f;
#pragma unroll
        for (int j = 0; j < 4; j++) {
            const int f = nb + wn * 64 + j * 16 + l16;
            const float bi = bias[f];
            const int hh = f >> 6, d = f & 63;
            bf16* dcol = dst + ((size_t)(bI * NHEAD + hh) * SEQ) * DEPTH + d;
#pragma unroll
            for (int mi = 0; mi < 8; mi++) {
                const int s0 = sBase + wm * 128 + (mi >> 2) * 64 + (mi & 3) * 16 + quad * 4;
#pragma unroll
                for (int r = 0; r < 4; r++)
                    dcol[(size_t)(s0 + r) * DEPTH] = (bf16)((acc[mi][j][r] + bi) * scl);
            }
        }
    } else {
#pragma unroll
        for (int j = 0; j < 4; j++) {
            const int f = nb + wn * 64 + j * 16 + l16;
            const float bi = bias[f];
            const int hh = f >> 6, d = f & 63;
            bf16* vrow = v + ((size_t)(bI * NHEAD + hh) * DEPTH + d) * SEQ;
#pragma unroll
            for (int mi = 0; mi < 8; mi++) {
                const int s0 = sBase + wm * 128 + (mi >> 2) * 64 + (mi & 3) * 16 + quad * 4;
                f32x4 a = acc[mi][j];
                bf16x4 ob = {(bf16)(a[0] + bi), (bf16)(a[1] + bi),
                             (bf16)(a[2] + bi), (bf16)(a[3] + bi)};
                *(bf16x4*)&vrow[s0] = ob;
            }
        }
    }
}

// ---------------------------------------------------------------------------
// Kernel 3: flash attention, R9 = R4's kv-split compute + PER-WAVE private
// double-buffered LDS staging, ZERO barriers in the main loop.
// Block = 64 q rows x head, 4 waves; kv tile 128; wave owns a 32-kv slice.
// In kv-split NO data is shared between waves: wave w reads only K rows
// [w*32, w*32+32) and V^T columns [w*32, w*32+32) of each tile.  So each
// wave stages its own 4 KB K-slice + 4 KB V-slice, x2 buffers = 16 KB/wave
// (64 KB/block).  Per half-step: { STAGE(next buf): 8 width-16 GLL ->
// s_waitcnt vmcnt(8) (prev buf landed, next in flight) -> sched_barrier ->
// compute cur buf }.  No __syncthreads -> no forced vmcnt(0) drain; each
// wave self-paces (the m97 barrier-drain ceiling does not apply).
// Swizzles (G21, both-sides): K phys chunk p of row r holds logical
// p^s(r), s(r)=((r&3)<<1)|((r>>3)&1); V [64][32] phys chunk p of row d
// holds logical p^(d&3).  Fragment reads land 2 lanes/bank (free).
// P stays in registers (R3/R4's verified token map).  Cross-wave
// kv-partial reduction at the end reuses the staging LDS (R4 verified).
// XCD pinning: block id = bh + 32*qb -> XCD bh%8, 4 heads = 2 MB KV / L2.
// ---------------------------------------------------------------------------
__global__ __launch_bounds__(256) void attn(const bf16* __restrict__ q,
                                            const bf16* __restrict__ k,
                                            const bf16* __restrict__ v,
                                            bf16* __restrict__ ctx) {
    __shared__ __align__(16) bf16 smb[32768];   // 64 KB: 4 waves x 16 KB
    const int tid = threadIdx.x;
    const int lane = tid & 63, wave = tid >> 6;
    const int quad = lane >> 4, l16 = lane & 15;
    const int bh = blockIdx.x;
    const int q0 = blockIdx.y * 64;
    const size_t hb = (size_t)bh * SEQ * DEPTH;
    const bf16* qh = q + hb;
    const bf16* kh = k + hb;            // [S][64]
    const bf16* vh = v + hb;            // [64][S]

    // Q as B-fragments: block's 64 q rows, shared by all waves
    bf16x8 bq_[4][2];
#pragma unroll
    for (int n = 0; n < 4; n++) {
        int qrow = q0 + n * 16 + l16;
#pragma unroll
        for (int c = 0; c < 2; c++)
            bq_[n][c] = *(const bf16x8*)&qh[(size_t)qrow * DEPTH + c * 32 + quad * 8];
    }

    f32x4 ov[4][4] = {};   // [d-tile][q-tile] kv-partial ctx^T
    f32x4 lv = {};         // [q-tile] quad-partial row sums

    // per-wave LDS bases (elems): K buf at wb + buf*2048, V at wb+4096+buf*2048
    const int wb = wave * 8192;
    // staging source swizzles
    const int kchS = (lane & 7) ^ (((lane >> 3) & 3) << 1);   // ^ (o&1) per o
    const int vchS = (lane & 3) ^ ((lane >> 2) & 3);
    // fragment-read geometry (R4 verified)
    const int krdL = ((l16 >> 2) << 3) + (l16 & 3);           // local row, + h*4
    const int ksw = ((l16 & 3) << 1) | ((l16 >> 2) & 1);      // = s(row)
    const int vsw = (quad ^ (l16 & 3)) << 3;                  // V read chunk

#define GLL(SRC, DST) __builtin_amdgcn_global_load_lds((gbl_void*)(SRC), (lds_void*)(DST), 16, 0, 0)

#define STAGE(BUF_, T_) { \
    _Pragma("unroll") \
    for (int o_ = 0; o_ < 4; o_++) { \
        const bf16* s_ = kh + (size_t)((T_) + wave * 32 + o_ * 8 + (lane >> 3)) * DEPTH \
                       + ((kchS ^ (o_ & 1)) << 3); \
        GLL(s_, smb + wb + (BUF_) * 2048 + o_ * 512 + lane * 8); \
    } \
    _Pragma("unroll") \
    for (int o_ = 0; o_ < 4; o_++) { \
        const bf16* s_ = vh + (size_t)(o_ * 16 + (lane >> 2)) * SEQ + (T_) + wave * 32 \
                       + (vchS << 3); \
        GLL(s_, smb + wb + 4096 + (BUF_) * 2048 + o_ * 512 + lane * 8); \
    } }

#define COMPUTE(BUF_) { \
    f32x4 s[2][4] = {}; \
    __builtin_amdgcn_s_setprio(1); \
    _Pragma("unroll") \
    for (int c_ = 0; c_ < 2; c_++) \
        _Pragma("unroll") \
        for (int h_ = 0; h_ < 2; h_++) { \
            bf16x8 kf = *(const bf16x8*)&smb[wb + (BUF_) * 2048 + (krdL + h_ * 4) * 64 \
                                             + ((((c_ << 2) | quad) ^ ksw) << 3)]; \
            _Pragma("unroll") \
            for (int n_ = 0; n_ < 4; n_++) \
                s[h_][n_] = __builtin_amdgcn_mfma_f32_16x16x32_bf16(kf, bq_[n_][c_], s[h_][n_], 0, 0, 0); \
        } \
    __builtin_amdgcn_s_setprio(0); \
    bf16x8 pb[4]; \
    _Pragma("unroll") \
    for (int n_ = 0; n_ < 4; n_++) { \
        float e0 = __builtin_amdgcn_exp2f(s[0][n_][0]); \
        float e1 = __builtin_amdgcn_exp2f(s[0][n_][1]); \
        float e2 = __builtin_amdgcn_exp2f(s[0][n_][2]); \
        float e3 = __builtin_amdgcn_exp2f(s[0][n_][3]); \
        float e4 = __builtin_amdgcn_exp2f(s[1][n_][0]); \
        float e5 = __builtin_amdgcn_exp2f(s[1][n_][1]); \
        float e6 = __builtin_amdgcn_exp2f(s[1][n_][2]); \
        float e7 = __builtin_amdgcn_exp2f(s[1][n_][3]); \
        pb[n_][0] = (bf16)e0; pb[n_][1] = (bf16)e1; \
        pb[n_][2] = (bf16)e2; pb[n_][3] = (bf16)e3; \
        pb[n_][4] = (bf16)e4; pb[n_][5] = (bf16)e5; \
        pb[n_][6] = (bf16)e6; pb[n_][7] = (bf16)e7; \
        lv[n_] += ((e0 + e1) + (e2 + e3)) + ((e4 + e5) + (e6 + e7)); \
    } \
    __builtin_amdgcn_s_setprio(1); \
    _Pragma("unroll") \
    for (int t_ = 0; t_ < 4; t_++) { \
        bf16x8 vf = *(const bf16x8*)&smb[wb + 4096 + (BUF_) * 2048 + (t_ * 16 + l16) * 32 + vsw]; \
        _Pragma("unroll") \
        for (int n_ = 0; n_ < 4; n_++) \
            ov[t_][n_] = __builtin_amdgcn_mfma_f32_16x16x32_bf16(vf, pb[n_], ov[t_][n_], 0, 0, 0); \
    } \
    __builtin_amdgcn_s_setprio(0); }

#define WAITV(N_) { asm volatile("s_waitcnt vmcnt(" #N_ ")" ::: "memory"); }
#define SB0 __builtin_amdgcn_sched_barrier(0)

    STAGE(0, 0);
#pragma unroll 1
    for (int tt = 0; tt < SEQ - 256; tt += 256) {
        STAGE(1, tt + 128);
        WAITV(8); SB0;
        COMPUTE(0); SB0;
        STAGE(0, tt + 256);
        WAITV(8); SB0;
        COMPUTE(1); SB0;
    }
    STAGE(1, SEQ - 128);
    WAITV(8); SB0;
    COMPUTE(0); SB0;
    WAITV(0); SB0;
    COMPUTE(1);

#undef SB0
#undef WAITV
#undef COMPUTE
#undef STAGE
#undef GLL

    // ---- cross-wave reduction of kv-partials (R4 verified; reuses LDS) ----
    f32x4* Red  = (f32x4*)smb;                       // [8 tiles][4 waves][64] 32 KB
    f32x4* Lred = (f32x4*)((char*)smb + 32768);      // [4 waves][64]           4 KB
    __syncthreads();
#pragma unroll
    for (int tt = 0; tt < 8; tt++)
        Red[(tt * 4 + wave) * 64 + lane] = ov[tt >> 2][tt & 3];
    Lred[wave * 64 + lane] = lv;
    __syncthreads();
    f32x4 ls = {};
#pragma unroll
    for (int w_ = 0; w_ < 4; w_++)
#pragma unroll
        for (int qd = 0; qd < 4; qd++)
            ls += Lred[w_ * 64 + qd * 16 + l16];
    const int b = bh >> 4, hh = bh & 15;
    const int wb1 = wave & 1;
#pragma unroll
    for (int u = 0; u < 2; u++) {
        int tt = wave * 2 + u;
        f32x4 sv = Red[(tt * 4 + 0) * 64 + lane] + Red[(tt * 4 + 1) * 64 + lane]
                 + Red[(tt * 4 + 2) * 64 + lane] + Red[(tt * 4 + 3) * 64 + lane];
        int n = wb1 * 2 + u, t = wave >> 1;
        float iv = 1.0f / (wb1 ? ls[2 + u] : ls[u]);
        bf16x4 ob = {(bf16)(sv[0] * iv), (bf16)(sv[1] * iv),
                     (bf16)(sv[2] * iv), (bf16)(sv[3] * iv)};
        size_t off = ((size_t)(b * SEQ + q0 + n * 16 + l16)) * D_MODEL
                   + hh * 64 + t * 16 + quad * 4;
        *(bf16x4*)&ctx[off] = ob;
    }
    __syncthreads();
#pragma unroll
    for (int tt = 8; tt < 16; tt++)
        Red[((tt - 8) * 4 + wave) * 64 + lane] = ov[tt >> 2][tt & 3];
    __syncthreads();
#pragma unroll
    for (int u = 0; u < 2; u++) {
        int rt = wave * 2 + u;
        f32x4 sv = Red[(rt * 4 + 0) * 64 + lane] + Red[(rt * 4 + 1) * 64 + lane]
                 + Red[(rt * 4 + 2) * 64 + lane] + Red[(rt * 4 + 3) * 64 + lane];
        int n = wb1 * 2 + u, t = 2 + (wave >> 1);
        float iv = 1.0f / (wb1 ? ls[2 + u] : ls[u]);
        bf16x4 ob = {(bf16)(sv[0] * iv), (bf16)(sv[1] * iv),
                     (bf16)(sv[2] * iv), (bf16)(sv[3] * iv)};
        size_t off = ((size_t)(b * SEQ + q0 + n * 16 + l16)) * D_MODEL
                   + hh * 64 + t * 16 + quad * 4;
        *(bf16x4*)&ctx[off] = ob;
    }
}

// ---------------------------------------------------------------------------
// Kernel 4: output projection (unchanged this round).
// ---------------------------------------------------------------------------
__global__ __launch_bounds__(256) void out_gemm(const bf16* __restrict__ ctx,
                                                const bf16* __restrict__ wot,
                                                const float* __restrict__ bo,
                                                float* __restrict__ out) {
    __shared__ bf16 As[64 * 32];
    __shared__ bf16 Bs[128 * 32];
    const int tid = threadIdx.x;
    const int lane = tid & 63, wave = tid >> 6;
    const int quad = lane >> 4, l16 = lane & 15;
    const int srow = lane >> 2, selem = (lane & 3) * 8;
    int row0 = blockIdx.y * 64, col0 = blockIdx.x * 128;
    f32x4 acc[4][2] = {};

    for (int k0 = 0; k0 < D_MODEL; k0 += 32) {
        __syncthreads();
        {
            const bf16* ga = ctx + (size_t)(row0 + wave * 16 + srow) * D_MODEL + k0 + selem;
            __builtin_amdgcn_global_load_lds((gbl_void*)ga, (lds_void*)(As + wave * 512 + lane * 8), 16, 0, 0);
        }
#pragma unroll
        for (int t = 0; t < 2; t++) {
            int m = wave * 2 + t;
            const bf16* gb = wot + (size_t)(col0 + m * 16 + srow) * D_MODEL + k0 + selem;
            __builtin_amdgcn_global_load_lds((gbl_void*)gb, (lds_void*)(Bs + m * 512 + lane * 8), 16, 0, 0);
        }
        __syncthreads();
        bf16x8 af[4], bfr[2];
#pragma unroll
        for (int i = 0; i < 4; i++)
            af[i] = *(const bf16x8*)&As[(i * 16 + l16) * 32 + quad * 8];
#pragma unroll
        for (int j = 0; j < 2; j++)
            bfr[j] = *(const bf16x8*)&Bs[(wave * 32 + j * 16 + l16) * 32 + quad * 8];
#pragma unroll
        for (int i = 0; i < 4; i++)
#pragma unroll
            for (int j = 0; j < 2; j++)
                acc[i][j] = __builtin_amdgcn_mfma_f32_16x16x32_bf16(af[i], bfr[j], acc[i][j], 0, 0, 0);
    }
#pragma unroll
    for (int i = 0; i < 4; i++)
#pragma unroll
        for (int j = 0; j < 2; j++) {
            int colg = col0 + wave * 32 + j * 16 + l16;
            float bi = bo[colg];
            int rbase = row0 + i * 16 + quad * 4;
#pragma unroll
            for (int r = 0; r < 4; r++)
                out[(size_t)(rbase + r) * D_MODEL + colg] = acc[i][j][r] + bi;
        }
}

// ---------------------------------------------------------------------------
extern "C" void kernel_launch(void* const* d_in, const int* in_sizes, int n_in,
                              void* d_out, int out_size, void* d_ws, size_t ws_size,
                              hipStream_t stream) {
    const float* x  = (const float*)d_in[0];
    const float* wq = (const float*)d_in[1];
    const float* bq = (const float*)d_in[2];
    const float* wk = (const float*)d_in[3];
    const float* bk = (const float*)d_in[4];
    const float* wv = (const float*)d_in[5];
    const float* bv = (const float*)d_in[6];
    const float* wo = (const float*)d_in[7];
    const float* bo = (const float*)d_in[8];
    float* out = (float*)d_out;

    const size_t MB = 1024 * 1024;
    char* ws = (char*)d_ws;
    bf16* xb  = (bf16*)(ws);             // [4096][1024]            8 MB
    bf16* wtb = (bf16*)(ws + 8 * MB);    // [4][1024][1024] (N,K)   8 MB
    bf16* qb  = (bf16*)(ws + 16 * MB);   // [B,H,S,64] (scaled)     8 MB
    bf16* kb  = (bf16*)(ws + 24 * MB);   // [B,H,S,64]              8 MB
    bf16* vb  = (bf16*)(ws + 32 * MB);   // [B,H,64,S]              8 MB
    bf16* ctx = (bf16*)(ws + 40 * MB);   // [4096][1024]            8 MB

    prep<<<dim3(32, 32, 8), dim3(32, 8), 0, stream>>>(wq, wk, wv, wo, x, wtb, xb);
    qkv_gemm<<<dim3(192), dim3(512), 0, stream>>>(xb, wtb, bq, bk, bv, qb, kb, vb);
    attn<<<dim3(BATCH * NHEAD, SEQ / 64), 256, 0, stream>>>(qb, kb, vb, ctx);
    out_gemm<<<dim3(8, 64), 256, 0, stream>>>(ctx, wtb + 3 * (size_t)D_MODEL * D_MODEL, bo, out);
}